// Round 5
// baseline (1348.825 us; speedup 1.0000x reference)
//
#include <hip/hip_runtime.h>

#define NN 32768
#define HWID 448
// H cols: 0:80 h | 80:160 hG1 | 160:240 hG2 | 240:249 f1 | 249:258 g1 | 258:267 f2 | 267:276 g2 |
//         276:280 pad | 280:360 hvo1 | 360:440 hvo2 | 440:448 pad

// ---- workspace float offsets ----
#define OFF_G     0
#define OFF_M     25600
#define OFF_FF    51200
#define OFF_FG    54080
#define OFF_CC    56960
#define OFF_C2    57284
#define OFF_CW    60164
#define OFF_STATS 133636
#define OFF_MS    133956
#define OFF_H     134148
#define OFF_U     14814212

__global__ __launch_bounds__(256) void k_prep_small(const float* __restrict__ qkvw,
                                                    const float* __restrict__ qkvb,
                                                    const float* __restrict__ outw,
                                                    float* __restrict__ ws) {
    int combo = blockIdx.y;
    int e = blockIdx.x * 256 + threadIdx.x;
    const float* Wq = qkvw + combo * 267 * 89;
    const float* Wk = Wq + 89 * 89;
    const float* Wv = Wq + 178 * 89;
    const float* bq = qkvb + combo * 267;
    const float* bk = bq + 89;
    const float* bv = bq + 178;
    const float* Wo = outw + combo * 89 * 89;
    if (e < 6400) {
        int a = e / 80, b = e % 80;
        float s = 0.f;
        for (int j = 0; j < 89; ++j) s += Wq[j*89+a] * Wk[j*89+b];
        ws[OFF_G + combo*6400 + e] = s;
    } else if (e < 12800) {
        int e2 = e - 6400; int f = e2 / 80, c = e2 % 80;
        float s = 0.f;
        for (int j = 0; j < 89; ++j) s += Wo[f*89+j] * Wv[j*89+c];
        ws[OFF_M + combo*6400 + e2] = s;
    } else if (e < 13520) {
        int e3 = e - 12800; int a = e3 / 9, t = e3 % 9;
        float s = 0.f;
        for (int j = 0; j < 89; ++j) s += Wq[j*89+a] * (Wk[j*89+80+t] + bk[j]);
        ws[OFF_FF + combo*720 + e3] = s;
    } else if (e < 14240) {
        int e4 = e - 13520; int a = e4 / 9, si = e4 % 9;
        float s = 0.f;
        for (int j = 0; j < 89; ++j) s += Wk[j*89+a] * (Wq[j*89+80+si] + bq[j]);
        ws[OFF_FG + combo*720 + e4] = s;
    } else if (e < 14321) {
        int e5 = e - 14240; int si = e5 / 9, t = e5 % 9;
        float s = 0.f;
        for (int j = 0; j < 89; ++j) s += (Wq[j*89+80+si] + bq[j]) * (Wk[j*89+80+t] + bk[j]);
        ws[OFF_CC + combo*81 + e5] = s;
    } else if (e < 15041) {
        int e6 = e - 14321; int t = e6 / 80, f = e6 % 80;
        float s = 0.f;
        for (int j = 0; j < 89; ++j) s += Wo[f*89+j] * (Wv[j*89+80+t] + bv[j]);
        ws[OFF_C2 + combo*720 + e6] = s;
    }
}

__global__ __launch_bounds__(256) void k_prep_cw(const float* __restrict__ W1,
                                                 const float* __restrict__ W2,
                                                 float* __restrict__ ws) {
    int l = blockIdx.y;
    int e = blockIdx.x * 256 + threadIdx.x;
    if (e >= 82 * 448) return;
    int k = e / 448, j = e % 448;
    int K = (l == 0) ? 82 : 80;
    float val = 0.f;
    if (k < K) {
        const float* Wr = ((l == 0) ? W1 : W2) + k * 80;
        if (j < 80) {
            val = Wr[j];
        } else if (j < 240) {
            int m = (j - 80) / 80, col = (j - 80) % 80;
            const float* G = ws + OFF_G + (l*2+m)*6400;
            float s = 0.f;
            for (int c = 0; c < 80; ++c) s += Wr[c] * G[c*80 + col];
            val = s;
        } else if (j < 276) {
            int q = j - 240; int m = q / 18; int qq = q % 18;
            int combo = l*2 + m;
            if (qq < 9) {
                const float* Ff = ws + OFF_FF + combo*720;
                float s = 0.f;
                for (int c = 0; c < 80; ++c) s += Wr[c] * Ff[c*9 + qq];
                val = s;
            } else {
                const float* Fg = ws + OFF_FG + combo*720;
                float s = 0.f;
                for (int c = 0; c < 80; ++c) s += Wr[c] * Fg[c*9 + qq - 9];
                val = s;
            }
        } else if (j >= 280 && j < 440) {
            int m = (j - 280) / 80, f = (j - 280) % 80;
            const float* M = ws + OFF_M + (l*2+m)*6400 + f*80;
            float s = 0.f;
            for (int c = 0; c < 80; ++c) s += Wr[c] * M[c];
            val = s;
        }
    }
    ws[OFF_CW + (size_t)l*82*448 + e] = val;
}

template<int K, bool TRANS>
__global__ __launch_bounds__(256) void k_gemm(const float* __restrict__ A,
                                              const float* __restrict__ CW,
                                              float* __restrict__ H,
                                              const float* __restrict__ ms) {
    __shared__ __align__(16) float AsT[K][72];
    __shared__ __align__(16) float Bs[K][68];
    int tid = threadIdx.x;
    int n0 = blockIdx.x * 64;
    int j0 = blockIdx.y * 64;
    float scale0 = 0.f;
    if constexpr (TRANS) scale0 = ms[80];
    for (int idx = tid; idx < 64 * K; idx += 256) {
        int r = idx / K, k = idx - r * K;
        float v = A[(size_t)(n0 + r) * K + k];
        if constexpr (TRANS) v = fmaxf(0.f, (v - ms[k]) * scale0);
        AsT[k][r] = v;
    }
    for (int idx = tid; idx < K * 64; idx += 256) {
        int k = idx >> 6, c = idx & 63;
        Bs[k][c] = CW[k * 448 + j0 + c];
    }
    __syncthreads();
    int r0 = (tid >> 4) * 4, c0 = (tid & 15) * 4;
    float acc[4][4] = {};
    for (int k = 0; k < K; ++k) {
        float4 a4 = *(const float4*)(&AsT[k][r0]);
        float4 b4 = *(const float4*)(&Bs[k][c0]);
        acc[0][0] += a4.x*b4.x; acc[0][1] += a4.x*b4.y; acc[0][2] += a4.x*b4.z; acc[0][3] += a4.x*b4.w;
        acc[1][0] += a4.y*b4.x; acc[1][1] += a4.y*b4.y; acc[1][2] += a4.y*b4.z; acc[1][3] += a4.y*b4.w;
        acc[2][0] += a4.z*b4.x; acc[2][1] += a4.z*b4.y; acc[2][2] += a4.z*b4.z; acc[2][3] += a4.z*b4.w;
        acc[3][0] += a4.w*b4.x; acc[3][1] += a4.w*b4.y; acc[3][2] += a4.w*b4.z; acc[3][3] += a4.w*b4.w;
    }
    for (int i = 0; i < 4; ++i) {
        float4 v = make_float4(acc[i][0], acc[i][1], acc[i][2], acc[i][3]);
        *(float4*)(&H[(size_t)(n0 + r0 + i) * HWID + j0 + c0]) = v;
    }
}

// ---------------- fused attention v3: 2 waves/block, 1 node/wave, 19.4 KB LDS -> 8 blocks/CU ----------------
__global__ __launch_bounds__(128, 4) void k_attn(const float* __restrict__ ws,
                                                 const float* __restrict__ Hbuf,
                                                 const int* __restrict__ nbr,
                                                 const float* __restrict__ outb,
                                                 const float* __restrict__ bvec,
                                                 float* __restrict__ u,
                                                 int l) {
    __shared__ __align__(16) float sS[2][9][242];  // h | hG1 | hG2 (cols 0:240), wave-private
    __shared__ float sP[2][2][9][9];
    __shared__ float sCC[2][81];
    int tid = threadIdx.x;
    int wave = tid >> 6, lane = tid & 63;
    int n = blockIdx.x * 2 + wave;
    int nv = nbr[n * 9 + (lane < 9 ? lane : 8)];
    int rr[9];
    #pragma unroll
    for (int s = 0; s < 9; ++s) rr[s] = __shfl(nv, s);

    // pair-1 (pp = lane < 81 always) f/g register prefetch
    int s1 = lane / 9, t1 = lane - s1 * 9;
    const float* rowS1 = Hbuf + (size_t)rr[s1] * HWID;
    const float* rowT1 = Hbuf + (size_t)rr[t1] * HWID;
    float f1a = rowS1[240 + t1], g1a = rowT1[249 + s1];
    float f2a = rowS1[258 + t1], g2a = rowT1[267 + s1];
    // pair-2 (pp2 = lane+64, valid for lane < 17)
    int pp2 = (lane < 17) ? (lane + 64) : 80;
    int s2 = pp2 / 9, t2 = pp2 - s2 * 9;
    const float* rowS2 = Hbuf + (size_t)rr[s2] * HWID;
    const float* rowT2 = Hbuf + (size_t)rr[t2] * HWID;
    float f1b = rowS2[240 + t2], g1b = rowT2[249 + s2];
    float f2b = rowS2[258 + t2], g2b = rowT2[267 + s2];

    // cc -> LDS (block-shared), staged cooperatively by all 128 threads
    for (int i = tid; i < 162; i += 128) sCC[0][i] = ws[OFF_CC + (l*2)*81 + i];  // [0][0..80],[1][0..80] contiguous

    // stage 9 rows x 240 floats (60 float4/row), coalesced
    for (int i = lane; i < 540; i += 64) {
        int row = i / 60, c4 = i - row * 60;
        int r = __shfl(nv, row);
        float4 v = *(const float4*)(Hbuf + (size_t)r * HWID + c4 * 4);
        *(float4*)(&sS[wave][row][c4 * 4]) = v;
    }
    __syncthreads();

    const float rsE = 1.0f / 9.433981132056603f;  // 1/sqrt(89)
    // phase A: pair 1
    {
        float a0 = 0.f, a1 = 0.f, b0 = 0.f, b1 = 0.f;
        #pragma unroll
        for (int i = 0; i < 20; ++i) {
            float4 hh = *(const float4*)(&sS[wave][t1][4*i]);
            float4 g1 = *(const float4*)(&sS[wave][s1][80 + 4*i]);
            float4 g2 = *(const float4*)(&sS[wave][s1][160 + 4*i]);
            a0 += g1.x*hh.x + g1.y*hh.y; a1 += g1.z*hh.z + g1.w*hh.w;
            b0 += g2.x*hh.x + g2.y*hh.y; b1 += g2.z*hh.z + g2.w*hh.w;
        }
        sP[wave][0][s1][t1] = (a0 + a1 + f1a + g1a + sCC[0][lane]) * rsE;
        sP[wave][1][s1][t1] = (b0 + b1 + f2a + g2a + sCC[1][lane]) * rsE;
    }
    // phase A: pair 2 (17 lanes)
    if (lane < 17) {
        float a0 = 0.f, a1 = 0.f, b0 = 0.f, b1 = 0.f;
        #pragma unroll
        for (int i = 0; i < 20; ++i) {
            float4 hh = *(const float4*)(&sS[wave][t2][4*i]);
            float4 g1 = *(const float4*)(&sS[wave][s2][80 + 4*i]);
            float4 g2 = *(const float4*)(&sS[wave][s2][160 + 4*i]);
            a0 += g1.x*hh.x + g1.y*hh.y; a1 += g1.z*hh.z + g1.w*hh.w;
            b0 += g2.x*hh.x + g2.y*hh.y; b1 += g2.z*hh.z + g2.w*hh.w;
        }
        sP[wave][0][s2][t2] = (a0 + a1 + f1b + g1b + sCC[0][pp2]) * rsE;
        sP[wave][1][s2][t2] = (b0 + b1 + f2b + g2b + sCC[1][pp2]) * rsE;
    }
    __syncthreads();
    // phase B: softmax over t (18 rows per node)
    if (lane < 18) {
        int m = lane / 9, s = lane - m*9;
        float row[9]; float mx = -1e30f;
        #pragma unroll
        for (int t = 0; t < 9; ++t) { row[t] = sP[wave][m][s][t]; mx = fmaxf(mx, row[t]); }
        float sm = 0.f;
        #pragma unroll
        for (int t = 0; t < 9; ++t) { row[t] = __expf(row[t] - mx); sm += row[t]; }
        float inv = 1.f / sm;
        #pragma unroll
        for (int t = 0; t < 9; ++t) sP[wave][m][s][t] = row[t] * inv;
    }
    __syncthreads();
    // phase C: PV (v from global, coalesced in f) + base(LDS) + max + bias
    for (int f = lane; f < 80; f += 64) {
        float acc[9] = {};
        #pragma unroll
        for (int m = 0; m < 2; ++m) {
            const float* c2 = ws + OFF_C2 + (l*2+m)*720;
            #pragma unroll
            for (int t = 0; t < 9; ++t) {
                float vv = Hbuf[(size_t)rr[t]*HWID + 280 + m*80 + f] + c2[t*80 + f];
                #pragma unroll
                for (int s = 0; s < 9; ++s) acc[s] += sP[wave][m][s][t] * vv;
            }
        }
        float mx = -1e30f;
        #pragma unroll
        for (int s = 0; s < 9; ++s) mx = fmaxf(mx, acc[s] + sS[wave][s][f]);
        float bias = outb[(l*2)*89 + f] + outb[(l*2+1)*89 + f] + bvec[f];
        u[(size_t)n*80 + f] = mx + bias;
    }
}

__global__ __launch_bounds__(256) void k_colreduce(const float* __restrict__ u, float* __restrict__ stats) {
    __shared__ float ps[3][80], ps2[3][80];
    int tid = threadIdx.x;
    int c = tid % 80, rg = tid / 80;
    if (rg < 3) {
        float s = 0.f, s2 = 0.f;
        int rbase = blockIdx.x * 48 + rg * 16;
        for (int i = 0; i < 16; ++i) {
            int rw = rbase + i;
            if (rw < NN) {
                float v = u[(size_t)rw*80 + c];
                s += v; s2 += v*v;
            }
        }
        ps[rg][c] = s; ps2[rg][c] = s2;
    }
    __syncthreads();
    if (tid < 80) {
        atomicAdd(&stats[tid],      ps[0][tid] + ps[1][tid] + ps[2][tid]);
        atomicAdd(&stats[80 + tid], ps2[0][tid] + ps2[1][tid] + ps2[2][tid]);
    }
}

__global__ __launch_bounds__(128) void k_normscale(const float* __restrict__ stats, float* __restrict__ ms) {
    __shared__ float red[80];
    int t = threadIdx.x;
    if (t < 80) {
        float mean = stats[t] * (1.0f / (float)NN);
        ms[t] = mean;
        red[t] = stats[80 + t] - (float)NN * mean * mean;
    }
    __syncthreads();
    if (t == 0) {
        float ss = 0.f;
        for (int i = 0; i < 80; ++i) ss += red[i];
        ms[80] = 1.0f / sqrtf(1e-5f + ss * (1.0f / (float)NN));
    }
}

__global__ __launch_bounds__(256) void k_final(const float* __restrict__ x,
                                               const float* __restrict__ u2,
                                               const float* __restrict__ ms,
                                               float* __restrict__ out) {
    int g = blockIdx.x * 256 + threadIdx.x;
    int n = g / 80, f = g % 80;
    float scale0 = ms[80];
    float v = fmaxf(0.f, (u2[g] - ms[f]) * scale0);
    float o = x[(size_t)n*82 + f] + v;
    if (f == 79 && (o > 1.0f || o < -1.0f)) o = 0.f;
    out[g] = o * 0.5f;
}

extern "C" void kernel_launch(void* const* d_in, const int* in_sizes, int n_in,
                              void* d_out, int out_size, void* d_ws, size_t ws_size,
                              hipStream_t stream) {
    const float* x    = (const float*)d_in[0];
    const float* W1   = (const float*)d_in[1];
    const float* b1   = (const float*)d_in[2];
    const float* W2   = (const float*)d_in[3];
    const float* b2   = (const float*)d_in[4];
    const float* qkvw = (const float*)d_in[5];
    const float* qkvb = (const float*)d_in[6];
    const float* outw = (const float*)d_in[7];
    const float* outb = (const float*)d_in[8];
    const int*   nbr  = (const int*)d_in[9];
    float* ws = (float*)d_ws;
    float* out = (float*)d_out;

    float* H = ws + OFF_H;
    float* u = ws + OFF_U;

    hipMemsetAsync(ws + OFF_STATS, 0, 320 * sizeof(float), stream);
    k_prep_small<<<dim3(59, 4), 256, 0, stream>>>(qkvw, qkvb, outw, ws);
    k_prep_cw<<<dim3(144, 2), 256, 0, stream>>>(W1, W2, ws);

    k_gemm<82, false><<<dim3(512, 7), 256, 0, stream>>>(x, ws + OFF_CW, H, nullptr);
    k_attn<<<16384, 128, 0, stream>>>(ws, H, nbr, outb, b1, u, 0);
    k_colreduce<<<683, 256, 0, stream>>>(u, ws + OFF_STATS);
    k_normscale<<<1, 128, 0, stream>>>(ws + OFF_STATS, ws + OFF_MS);

    k_gemm<80, true><<<dim3(512, 7), 256, 0, stream>>>(u, ws + OFF_CW + 82*448, H, ws + OFF_MS);
    k_attn<<<16384, 128, 0, stream>>>(ws, H, nbr, outb, b2, u, 1);
    k_colreduce<<<683, 256, 0, stream>>>(u, ws + OFF_STATS + 160);
    k_normscale<<<1, 128, 0, stream>>>(ws + OFF_STATS + 160, ws + OFF_MS + 96);

    k_final<<<10240, 256, 0, stream>>>(x, u, ws + OFF_MS + 96, out);
}

// Round 6
// 600.629 us; speedup vs baseline: 2.2457x; 2.2457x over previous
//
#include <hip/hip_runtime.h>

#define NN 32768
#define HWID 448
// H cols: 0:80 h | 80:160 hG1 | 160:240 hG2 | 240:249 f1 | 249:258 g1 | 258:267 f2 | 267:276 g2 |
//         276:280 pad | 280:360 hvo1 | 360:440 hvo2 | 440:448 pad

// ---- workspace float offsets ----
#define OFF_G     0
#define OFF_M     25600
#define OFF_FF    51200
#define OFF_FG    54080
#define OFF_CC    56960
#define OFF_C2    57284
#define OFF_CW    60164
#define OFF_STATS 133636
#define OFF_MS    133956
#define OFF_H     134148
#define OFF_U     14814212

__global__ __launch_bounds__(256) void k_prep_small(const float* __restrict__ qkvw,
                                                    const float* __restrict__ qkvb,
                                                    const float* __restrict__ outw,
                                                    float* __restrict__ ws) {
    int combo = blockIdx.y;
    int e = blockIdx.x * 256 + threadIdx.x;
    const float* Wq = qkvw + combo * 267 * 89;
    const float* Wk = Wq + 89 * 89;
    const float* Wv = Wq + 178 * 89;
    const float* bq = qkvb + combo * 267;
    const float* bk = bq + 89;
    const float* bv = bq + 178;
    const float* Wo = outw + combo * 89 * 89;
    if (e < 6400) {
        int a = e / 80, b = e % 80;
        float s = 0.f;
        for (int j = 0; j < 89; ++j) s += Wq[j*89+a] * Wk[j*89+b];
        ws[OFF_G + combo*6400 + e] = s;
    } else if (e < 12800) {
        int e2 = e - 6400; int f = e2 / 80, c = e2 % 80;
        float s = 0.f;
        for (int j = 0; j < 89; ++j) s += Wo[f*89+j] * Wv[j*89+c];
        ws[OFF_M + combo*6400 + e2] = s;
    } else if (e < 13520) {
        int e3 = e - 12800; int a = e3 / 9, t = e3 % 9;
        float s = 0.f;
        for (int j = 0; j < 89; ++j) s += Wq[j*89+a] * (Wk[j*89+80+t] + bk[j]);
        ws[OFF_FF + combo*720 + e3] = s;
    } else if (e < 14240) {
        int e4 = e - 13520; int a = e4 / 9, si = e4 % 9;
        float s = 0.f;
        for (int j = 0; j < 89; ++j) s += Wk[j*89+a] * (Wq[j*89+80+si] + bq[j]);
        ws[OFF_FG + combo*720 + e4] = s;
    } else if (e < 14321) {
        int e5 = e - 14240; int si = e5 / 9, t = e5 % 9;
        float s = 0.f;
        for (int j = 0; j < 89; ++j) s += (Wq[j*89+80+si] + bq[j]) * (Wk[j*89+80+t] + bk[j]);
        ws[OFF_CC + combo*81 + e5] = s;
    } else if (e < 15041) {
        int e6 = e - 14321; int t = e6 / 80, f = e6 % 80;
        float s = 0.f;
        for (int j = 0; j < 89; ++j) s += Wo[f*89+j] * (Wv[j*89+80+t] + bv[j]);
        ws[OFF_C2 + combo*720 + e6] = s;
    }
}

__global__ __launch_bounds__(256) void k_prep_cw(const float* __restrict__ W1,
                                                 const float* __restrict__ W2,
                                                 float* __restrict__ ws) {
    int l = blockIdx.y;
    int e = blockIdx.x * 256 + threadIdx.x;
    if (e >= 82 * 448) return;
    int k = e / 448, j = e % 448;
    int K = (l == 0) ? 82 : 80;
    float val = 0.f;
    if (k < K) {
        const float* Wr = ((l == 0) ? W1 : W2) + k * 80;
        if (j < 80) {
            val = Wr[j];
        } else if (j < 240) {
            int m = (j - 80) / 80, col = (j - 80) % 80;
            const float* G = ws + OFF_G + (l*2+m)*6400;
            float s = 0.f;
            for (int c = 0; c < 80; ++c) s += Wr[c] * G[c*80 + col];
            val = s;
        } else if (j < 276) {
            int q = j - 240; int m = q / 18; int qq = q % 18;
            int combo = l*2 + m;
            if (qq < 9) {
                const float* Ff = ws + OFF_FF + combo*720;
                float s = 0.f;
                for (int c = 0; c < 80; ++c) s += Wr[c] * Ff[c*9 + qq];
                val = s;
            } else {
                const float* Fg = ws + OFF_FG + combo*720;
                float s = 0.f;
                for (int c = 0; c < 80; ++c) s += Wr[c] * Fg[c*9 + qq - 9];
                val = s;
            }
        } else if (j >= 280 && j < 440) {
            int m = (j - 280) / 80, f = (j - 280) % 80;
            const float* M = ws + OFF_M + (l*2+m)*6400 + f*80;
            float s = 0.f;
            for (int c = 0; c < 80; ++c) s += Wr[c] * M[c];
            val = s;
        }
    }
    ws[OFF_CW + (size_t)l*82*448 + e] = val;
}

template<int K, bool TRANS>
__global__ __launch_bounds__(256) void k_gemm(const float* __restrict__ A,
                                              const float* __restrict__ CW,
                                              float* __restrict__ H,
                                              const float* __restrict__ ms) {
    __shared__ __align__(16) float AsT[K][72];
    __shared__ __align__(16) float Bs[K][68];
    int tid = threadIdx.x;
    int n0 = blockIdx.x * 64;
    int j0 = blockIdx.y * 64;
    float scale0 = 0.f;
    if constexpr (TRANS) scale0 = ms[80];
    for (int idx = tid; idx < 64 * K; idx += 256) {
        int r = idx / K, k = idx - r * K;
        float v = A[(size_t)(n0 + r) * K + k];
        if constexpr (TRANS) v = fmaxf(0.f, (v - ms[k]) * scale0);
        AsT[k][r] = v;
    }
    for (int idx = tid; idx < K * 64; idx += 256) {
        int k = idx >> 6, c = idx & 63;
        Bs[k][c] = CW[k * 448 + j0 + c];
    }
    __syncthreads();
    int r0 = (tid >> 4) * 4, c0 = (tid & 15) * 4;
    float acc[4][4] = {};
    for (int k = 0; k < K; ++k) {
        float4 a4 = *(const float4*)(&AsT[k][r0]);
        float4 b4 = *(const float4*)(&Bs[k][c0]);
        acc[0][0] += a4.x*b4.x; acc[0][1] += a4.x*b4.y; acc[0][2] += a4.x*b4.z; acc[0][3] += a4.x*b4.w;
        acc[1][0] += a4.y*b4.x; acc[1][1] += a4.y*b4.y; acc[1][2] += a4.y*b4.z; acc[1][3] += a4.y*b4.w;
        acc[2][0] += a4.z*b4.x; acc[2][1] += a4.z*b4.y; acc[2][2] += a4.z*b4.z; acc[2][3] += a4.z*b4.w;
        acc[3][0] += a4.w*b4.x; acc[3][1] += a4.w*b4.y; acc[3][2] += a4.w*b4.z; acc[3][3] += a4.w*b4.w;
    }
    for (int i = 0; i < 4; ++i) {
        float4 v = make_float4(acc[i][0], acc[i][1], acc[i][2], acc[i][3]);
        *(float4*)(&H[(size_t)(n0 + r0 + i) * HWID + j0 + c0]) = v;
    }
}

// ---------------- fused attention v3b: 2 waves/block, 1 node/wave, 19.4 KB LDS ----------------
// NOTE: no min-waves arg in __launch_bounds__ — R5's (128,4) forced VGPR->64 and
// spilled ~550B/thread to scratch (WRITE_SIZE 10MB->1.14GB). Let LDS bound occupancy.
__global__ __launch_bounds__(128) void k_attn(const float* __restrict__ ws,
                                              const float* __restrict__ Hbuf,
                                              const int* __restrict__ nbr,
                                              const float* __restrict__ outb,
                                              const float* __restrict__ bvec,
                                              float* __restrict__ u,
                                              int l) {
    __shared__ __align__(16) float sS[2][9][242];  // h | hG1 | hG2 (cols 0:240), wave-private
    __shared__ float sP[2][2][9][9];
    __shared__ float sCC[2][81];
    int tid = threadIdx.x;
    int wave = tid >> 6, lane = tid & 63;
    int n = blockIdx.x * 2 + wave;
    int nv = nbr[n * 9 + (lane < 9 ? lane : 8)];
    int rr[9];
    #pragma unroll
    for (int s = 0; s < 9; ++s) rr[s] = __shfl(nv, s);

    // pair-1 (pp = lane < 81 always) f/g register prefetch
    int s1 = lane / 9, t1 = lane - s1 * 9;
    const float* rowS1 = Hbuf + (size_t)rr[s1] * HWID;
    const float* rowT1 = Hbuf + (size_t)rr[t1] * HWID;
    float f1a = rowS1[240 + t1], g1a = rowT1[249 + s1];
    float f2a = rowS1[258 + t1], g2a = rowT1[267 + s1];
    // pair-2 (pp2 = lane+64, valid for lane < 17)
    int pp2 = (lane < 17) ? (lane + 64) : 80;
    int s2 = pp2 / 9, t2 = pp2 - s2 * 9;
    const float* rowS2 = Hbuf + (size_t)rr[s2] * HWID;
    const float* rowT2 = Hbuf + (size_t)rr[t2] * HWID;
    float f1b = rowS2[240 + t2], g1b = rowT2[249 + s2];
    float f2b = rowS2[258 + t2], g2b = rowT2[267 + s2];

    // cc -> LDS (block-shared)
    for (int i = tid; i < 162; i += 128) sCC[0][i] = ws[OFF_CC + (l*2)*81 + i];

    // stage 9 rows x 240 floats (60 float4/row), coalesced
    for (int i = lane; i < 540; i += 64) {
        int row = i / 60, c4 = i - row * 60;
        int r = __shfl(nv, row);
        float4 v = *(const float4*)(Hbuf + (size_t)r * HWID + c4 * 4);
        *(float4*)(&sS[wave][row][c4 * 4]) = v;
    }
    __syncthreads();

    const float rsE = 1.0f / 9.433981132056603f;  // 1/sqrt(89)
    // phase A: pair 1
    {
        float a0 = 0.f, a1 = 0.f, b0 = 0.f, b1 = 0.f;
        #pragma unroll
        for (int i = 0; i < 20; ++i) {
            float4 hh = *(const float4*)(&sS[wave][t1][4*i]);
            float4 g1 = *(const float4*)(&sS[wave][s1][80 + 4*i]);
            float4 g2 = *(const float4*)(&sS[wave][s1][160 + 4*i]);
            a0 += g1.x*hh.x + g1.y*hh.y; a1 += g1.z*hh.z + g1.w*hh.w;
            b0 += g2.x*hh.x + g2.y*hh.y; b1 += g2.z*hh.z + g2.w*hh.w;
        }
        sP[wave][0][s1][t1] = (a0 + a1 + f1a + g1a + sCC[0][lane]) * rsE;
        sP[wave][1][s1][t1] = (b0 + b1 + f2a + g2a + sCC[1][lane]) * rsE;
    }
    // phase A: pair 2 (17 lanes)
    if (lane < 17) {
        float a0 = 0.f, a1 = 0.f, b0 = 0.f, b1 = 0.f;
        #pragma unroll
        for (int i = 0; i < 20; ++i) {
            float4 hh = *(const float4*)(&sS[wave][t2][4*i]);
            float4 g1 = *(const float4*)(&sS[wave][s2][80 + 4*i]);
            float4 g2 = *(const float4*)(&sS[wave][s2][160 + 4*i]);
            a0 += g1.x*hh.x + g1.y*hh.y; a1 += g1.z*hh.z + g1.w*hh.w;
            b0 += g2.x*hh.x + g2.y*hh.y; b1 += g2.z*hh.z + g2.w*hh.w;
        }
        sP[wave][0][s2][t2] = (a0 + a1 + f1b + g1b + sCC[0][pp2]) * rsE;
        sP[wave][1][s2][t2] = (b0 + b1 + f2b + g2b + sCC[1][pp2]) * rsE;
    }
    __syncthreads();
    // phase B: softmax over t (18 rows per node)
    if (lane < 18) {
        int m = lane / 9, s = lane - m*9;
        float row[9]; float mx = -1e30f;
        #pragma unroll
        for (int t = 0; t < 9; ++t) { row[t] = sP[wave][m][s][t]; mx = fmaxf(mx, row[t]); }
        float sm = 0.f;
        #pragma unroll
        for (int t = 0; t < 9; ++t) { row[t] = __expf(row[t] - mx); sm += row[t]; }
        float inv = 1.f / sm;
        #pragma unroll
        for (int t = 0; t < 9; ++t) sP[wave][m][s][t] = row[t] * inv;
    }
    __syncthreads();
    // phase C: PV (v from global, coalesced in f) + base(LDS) + max + bias
    for (int f = lane; f < 80; f += 64) {
        float acc[9] = {};
        #pragma unroll
        for (int m = 0; m < 2; ++m) {
            const float* c2 = ws + OFF_C2 + (l*2+m)*720;
            #pragma unroll
            for (int t = 0; t < 9; ++t) {
                float vv = Hbuf[(size_t)rr[t]*HWID + 280 + m*80 + f] + c2[t*80 + f];
                #pragma unroll
                for (int s = 0; s < 9; ++s) acc[s] += sP[wave][m][s][t] * vv;
            }
        }
        float mx = -1e30f;
        #pragma unroll
        for (int s = 0; s < 9; ++s) mx = fmaxf(mx, acc[s] + sS[wave][s][f]);
        float bias = outb[(l*2)*89 + f] + outb[(l*2+1)*89 + f] + bvec[f];
        u[(size_t)n*80 + f] = mx + bias;
    }
}

__global__ __launch_bounds__(256) void k_colreduce(const float* __restrict__ u, float* __restrict__ stats) {
    __shared__ float ps[3][80], ps2[3][80];
    int tid = threadIdx.x;
    int c = tid % 80, rg = tid / 80;
    if (rg < 3) {
        float s = 0.f, s2 = 0.f;
        int rbase = blockIdx.x * 48 + rg * 16;
        for (int i = 0; i < 16; ++i) {
            int rw = rbase + i;
            if (rw < NN) {
                float v = u[(size_t)rw*80 + c];
                s += v; s2 += v*v;
            }
        }
        ps[rg][c] = s; ps2[rg][c] = s2;
    }
    __syncthreads();
    if (tid < 80) {
        atomicAdd(&stats[tid],      ps[0][tid] + ps[1][tid] + ps[2][tid]);
        atomicAdd(&stats[80 + tid], ps2[0][tid] + ps2[1][tid] + ps2[2][tid]);
    }
}

__global__ __launch_bounds__(128) void k_normscale(const float* __restrict__ stats, float* __restrict__ ms) {
    __shared__ float red[80];
    int t = threadIdx.x;
    if (t < 80) {
        float mean = stats[t] * (1.0f / (float)NN);
        ms[t] = mean;
        red[t] = stats[80 + t] - (float)NN * mean * mean;
    }
    __syncthreads();
    if (t == 0) {
        float ss = 0.f;
        for (int i = 0; i < 80; ++i) ss += red[i];
        ms[80] = 1.0f / sqrtf(1e-5f + ss * (1.0f / (float)NN));
    }
}

__global__ __launch_bounds__(256) void k_final(const float* __restrict__ x,
                                               const float* __restrict__ u2,
                                               const float* __restrict__ ms,
                                               float* __restrict__ out) {
    int g = blockIdx.x * 256 + threadIdx.x;
    int n = g / 80, f = g % 80;
    float scale0 = ms[80];
    float v = fmaxf(0.f, (u2[g] - ms[f]) * scale0);
    float o = x[(size_t)n*82 + f] + v;
    if (f == 79 && (o > 1.0f || o < -1.0f)) o = 0.f;
    out[g] = o * 0.5f;
}

extern "C" void kernel_launch(void* const* d_in, const int* in_sizes, int n_in,
                              void* d_out, int out_size, void* d_ws, size_t ws_size,
                              hipStream_t stream) {
    const float* x    = (const float*)d_in[0];
    const float* W1   = (const float*)d_in[1];
    const float* b1   = (const float*)d_in[2];
    const float* W2   = (const float*)d_in[3];
    const float* b2   = (const float*)d_in[4];
    const float* qkvw = (const float*)d_in[5];
    const float* qkvb = (const float*)d_in[6];
    const float* outw = (const float*)d_in[7];
    const float* outb = (const float*)d_in[8];
    const int*   nbr  = (const int*)d_in[9];
    float* ws = (float*)d_ws;
    float* out = (float*)d_out;

    float* H = ws + OFF_H;
    float* u = ws + OFF_U;

    hipMemsetAsync(ws + OFF_STATS, 0, 320 * sizeof(float), stream);
    k_prep_small<<<dim3(59, 4), 256, 0, stream>>>(qkvw, qkvb, outw, ws);
    k_prep_cw<<<dim3(144, 2), 256, 0, stream>>>(W1, W2, ws);

    k_gemm<82, false><<<dim3(512, 7), 256, 0, stream>>>(x, ws + OFF_CW, H, nullptr);
    k_attn<<<16384, 128, 0, stream>>>(ws, H, nbr, outb, b1, u, 0);
    k_colreduce<<<683, 256, 0, stream>>>(u, ws + OFF_STATS);
    k_normscale<<<1, 128, 0, stream>>>(ws + OFF_STATS, ws + OFF_MS);

    k_gemm<80, true><<<dim3(512, 7), 256, 0, stream>>>(u, ws + OFF_CW + 82*448, H, ws + OFF_MS);
    k_attn<<<16384, 128, 0, stream>>>(ws, H, nbr, outb, b2, u, 1);
    k_colreduce<<<683, 256, 0, stream>>>(u, ws + OFF_STATS + 160);
    k_normscale<<<1, 128, 0, stream>>>(ws + OFF_STATS + 160, ws + OFF_MS + 96);

    k_final<<<10240, 256, 0, stream>>>(x, u, ws + OFF_MS + 96, out);
}